// Round 7
// baseline (257.241 us; speedup 1.0000x reference)
//
#include <hip/hip_runtime.h>
#include <math.h>

#define T_TOK 8192
#define A_DIM 1024
#define E_DIM 512
#define S_SPAN 32768
#define HID 150

typedef __attribute__((ext_vector_type(8))) short short8;
typedef __attribute__((ext_vector_type(4))) float f32x4;
typedef __attribute__((ext_vector_type(4))) unsigned int u32x4;

__device__ __forceinline__ unsigned short f2bf(float f) {
    unsigned int u = __builtin_bit_cast(unsigned int, f);
    u += 0x7FFFu + ((u >> 16) & 1u);          // RNE
    return (unsigned short)(u >> 16);
}
__device__ __forceinline__ float bf2f(unsigned int h16) {
    unsigned int u = h16 << 16;
    return __builtin_bit_cast(float, u);
}
__device__ __forceinline__ short8 cast8(f32x4 a, f32x4 b) {
    short8 r;
    r[0] = (short)f2bf(a.x); r[1] = (short)f2bf(a.y);
    r[2] = (short)f2bf(a.z); r[3] = (short)f2bf(a.w);
    r[4] = (short)f2bf(b.x); r[5] = (short)f2bf(b.y);
    r[6] = (short)f2bf(b.z); r[7] = (short)f2bf(b.w);
    return r;
}

// ---------------------------------------------------------------------------
// prep: weight transposes via LDS 64x64 tiles (coalesced both sides)
// + width projection (+bs1 folded, stride 160, zero-padded).
// ---------------------------------------------------------------------------
struct WConv { const float* src; unsigned short* dst; int K0; int Kpad; int nblk; };
struct PrepTab {
    WConv g[6];
    const float* wt; const float* Ws1w; const float* bs1; float* PW;
};

__global__ __launch_bounds__(256) void prep_kernel(PrepTab tab) {
    __shared__ float tl[64][65];                 // stride 65: conflict-free transpose
    int b = blockIdx.x;
    #pragma unroll
    for (int gi = 0; gi < 6; ++gi) {
        if (b < tab.g[gi].nblk) {
            const int kt   = tab.g[gi].Kpad >> 6;        // k-tiles
            const int j0   = (b / kt) * 64;              // output-row tile base
            const int k0   = (b % kt) * 64;              // k tile base
            const int K0   = tab.g[gi].K0;
            const int Kpad = tab.g[gi].Kpad;
            const int ty = threadIdx.x >> 6, tx = threadIdx.x & 63;
            const float* src = tab.g[gi].src;
            #pragma unroll
            for (int r = 0; r < 16; ++r) {               // coalesced src reads
                int k = k0 + ty * 16 + r;
                int j = j0 + tx;
                tl[ty * 16 + r][tx] = (j < HID && k < K0)
                                      ? src[(size_t)k * HID + j] : 0.f;
            }
            __syncthreads();
            unsigned short* dst = tab.g[gi].dst;
            #pragma unroll
            for (int r = 0; r < 16; ++r) {               // coalesced dst writes
                int j = j0 + ty * 16 + r;
                if (j < 160)
                    dst[(size_t)j * Kpad + k0 + tx] = f2bf(tl[tx][ty * 16 + r]);
            }
            return;
        }
        b -= tab.g[gi].nblk;
    }
    // width projection: 9 blocks. PW row = width_table[b] @ Ws1w + bs1,
    // stride 160 with exact zeros at j>=150.
    int j = threadIdx.x;
    if (j < 160) {
        float acc = 0.f;
        if (j < HID) {
            for (int k = 0; k < 20; ++k)
                acc = fmaf(tab.wt[b * 20 + k], tab.Ws1w[k * HID + j], acc);
            acc += tab.bs1[j];
        }
        tab.PW[b * 160 + j] = acc;
    }
}

// ---------------------------------------------------------------------------
// unified MFMA GEMM — DIRECT-STREAM (r7): no LDS W-staging, no barriers.
// Rationale: the LDS path cost 20 ds_read_b128 (~240 cyc) per 100 cyc of
// MFMA per chunk + 2.3M bank conflicts + barrier lockstep. W is L2-resident
// (<=320 KB/group, every CU re-reads it; ~140 MB L2 traffic ~= 4 us at
// 34.5 TB/s), so each wave reads B fragments straight from global — the
// pattern already proven by the span-l2 GEMM (K=160, W2 direct). With no
// barriers the compiler software-pipelines chunk c+1 loads under chunk c
// MFMAs, and waves free-run. Works for ANY nch (odd-tail hazard gone).
// Accumulation order per acc[nt] unchanged (chunk ascending, half 0 then 1)
// -> bit-identical to all previous rounds.
// W2 path — fused attn layer2+3 in group-0 epilogue (per-wave LDS tile).
// ---------------------------------------------------------------------------
struct GG {
    const void* A; int lda;
    const unsigned short* W; int K; int nrb;
    unsigned short* outh; int ldo;
    const float* bias; int relu;
    const float* dotv; const float* dotb; float* dotout;
    const unsigned short* W2; const float* bias2;
};
struct GTab { GG g[4]; int ng; };

template <int TAG, bool AF32>
__global__ __launch_bounds__(256) void gemm_fused(GTab tab) {
    constexpr int LDH = 168;
    __shared__ unsigned short tileAll[4][16 * LDH];   // W2 epilogue only (21.5 KB)

    int b = blockIdx.x;
    int gi = 0;
    while (gi < tab.ng - 1 && b >= tab.g[gi].nrb) { b -= tab.g[gi].nrb; ++gi; }
    const GG G = tab.g[gi];

    const int tid = threadIdx.x;
    const int wid = tid >> 6;
    const int lane = tid & 63;
    const int l15 = lane & 15;
    const int quad = lane >> 4;
    const int row0 = b * 64 + wid * 16 + l15;
    const int K = G.K;
    const int nch = K >> 6;                       // 16 (K=1024), 8 (512), 3 (192)
    const float* Af = (const float*)G.A + (size_t)row0 * G.lda;
    const unsigned short* Ah = (const unsigned short*)G.A + (size_t)row0 * G.lda;
    const unsigned short* Wr = G.W + (size_t)l15 * K;   // B row l15 of each nt tile

    f32x4 acc[10];
    #pragma unroll
    for (int nt = 0; nt < 10; ++nt) acc[nt] = (f32x4){0.f, 0.f, 0.f, 0.f};

    for (int c = 0; c < nch; ++c) {
        const int kb = c << 6;
        short8 avc0, avc1;
        if (AF32) {
            f32x4 f0 = *(const f32x4*)(Af + kb + quad * 8);
            f32x4 f1 = *(const f32x4*)(Af + kb + quad * 8 + 4);
            f32x4 f2 = *(const f32x4*)(Af + kb + 32 + quad * 8);
            f32x4 f3 = *(const f32x4*)(Af + kb + 32 + quad * 8 + 4);
            avc0 = cast8(f0, f1);
            avc1 = cast8(f2, f3);
        } else {
            avc0 = *(const short8*)(Ah + kb + quad * 8);
            avc1 = *(const short8*)(Ah + kb + 32 + quad * 8);
        }
        #pragma unroll
        for (int nt = 0; nt < 10; ++nt) {
            // 4-lane quads read 64B contiguous; 16 rows K*2 bytes apart (L2-hit)
            short8 bv0 = *(const short8*)(Wr + (size_t)nt * 16 * K + kb + quad * 8);
            acc[nt] = __builtin_amdgcn_mfma_f32_16x16x32_bf16(avc0, bv0, acc[nt], 0, 0, 0);
            short8 bv1 = *(const short8*)(Wr + (size_t)nt * 16 * K + kb + 32 + quad * 8);
            acc[nt] = __builtin_amdgcn_mfma_f32_16x16x32_bf16(avc1, bv1, acc[nt], 0, 0, 0);
        }
    }

    const int rbase = b * 64 + wid * 16 + quad * 4;
    if (G.W2) {
        // ---- fused attn layer2+3 (per-wave LDS tile; same-wave RAW, no barrier) ----
        unsigned short* tile = tileAll[wid];
        #pragma unroll
        for (int nt = 0; nt < 10; ++nt) {
            int col = nt * 16 + l15;
            float bv_ = (col < HID) ? G.bias[col] : 0.f;
            #pragma unroll
            for (int r = 0; r < 4; ++r) {
                float v = fmaxf(acc[nt][r] + bv_, 0.f);
                tile[(quad * 4 + r) * LDH + col] = f2bf(v);
            }
        }
        f32x4 acc2[10];
        #pragma unroll
        for (int nt = 0; nt < 10; ++nt) acc2[nt] = (f32x4){0.f, 0.f, 0.f, 0.f};
        #pragma unroll
        for (int kc = 0; kc < 5; ++kc) {
            short8 av = *(const short8*)&tile[l15 * LDH + kc * 32 + quad * 8];
            #pragma unroll
            for (int nt = 0; nt < 10; ++nt) {
                short8 bv = *(const short8*)(G.W2 + (size_t)(nt * 16 + l15) * 192 + kc * 32 + quad * 8);
                acc2[nt] = __builtin_amdgcn_mfma_f32_16x16x32_bf16(av, bv, acc2[nt], 0, 0, 0);
            }
        }
        float part[4] = {0.f, 0.f, 0.f, 0.f};
        #pragma unroll
        for (int nt = 0; nt < 10; ++nt) {
            int col = nt * 16 + l15;
            float b2 = (col < HID) ? G.bias2[col] : 0.f;
            float vv = (col < HID) ? G.dotv[col] : 0.f;
            #pragma unroll
            for (int r = 0; r < 4; ++r)
                part[r] += fmaxf(acc2[nt][r] + b2, 0.f) * vv;
        }
        #pragma unroll
        for (int r = 0; r < 4; ++r) {
            float p = part[r];
            #pragma unroll
            for (int off = 1; off < 16; off <<= 1) p += __shfl_xor(p, off);
            if (l15 == 0) G.dotout[rbase + r] = p + G.dotb[0];
        }
    } else if (G.dotout) {
        float part[4] = {0.f, 0.f, 0.f, 0.f};
        #pragma unroll
        for (int nt = 0; nt < 10; ++nt) {
            int col = nt * 16 + l15;
            float bv_ = (col < HID) ? G.bias[col] : 0.f;
            float vv = (col < HID) ? G.dotv[col] : 0.f;
            #pragma unroll
            for (int r = 0; r < 4; ++r)
                part[r] += fmaxf(acc[nt][r] + bv_, 0.f) * vv;
        }
        #pragma unroll
        for (int r = 0; r < 4; ++r) {
            float p = part[r];
            #pragma unroll
            for (int off = 1; off < 16; off <<= 1) p += __shfl_xor(p, off);
            if (l15 == 0) G.dotout[rbase + r] = p + G.dotb[0];
        }
    } else {
        #pragma unroll
        for (int nt = 0; nt < 10; ++nt) {
            int col = nt * 16 + l15;
            float bv_ = (G.bias != nullptr && col < HID) ? G.bias[col] : 0.f;
            #pragma unroll
            for (int r = 0; r < 4; ++r) {
                int row = rbase + r;
                float v = acc[nt][r] + bv_;
                if (G.relu) v = fmaxf(v, 0.f);
                G.outh[(size_t)row * G.ldo + col] = f2bf(v);
            }
        }
    }
}

// ---------------------------------------------------------------------------
// span layer-1 (2048 blocks, 32 waves/CU): one span per 16-lane group.
// r7: dwordx4 gathers — thread hl handles 16B chunk hl (and 16+hl if hl<4):
// 12 x4-gathers/round vs 60 u32 gathers before (~2.5x fewer VMEM instrs).
// Same per-element FMA chain (pw + ps + pe, then l=0..9) -> bit-identical.
// Chunks 16..19 cover cols 128..159; cols 150..159 compute exact zeros
// (PW/Psh/Peh/Pmh pads are exact zeros) over gemm3's exact-zero B rows.
// ---------------------------------------------------------------------------
__device__ __forceinline__ void add_bf8(f32x4& A, f32x4& B, u32x4 u) {
    A.x += bf2f(u.x & 0xffff); A.y += bf2f(u.x >> 16);
    A.z += bf2f(u.y & 0xffff); A.w += bf2f(u.y >> 16);
    B.x += bf2f(u.z & 0xffff); B.y += bf2f(u.z >> 16);
    B.z += bf2f(u.w & 0xffff); B.w += bf2f(u.w >> 16);
}
__device__ __forceinline__ void fma_bf8(f32x4& A, f32x4& B, u32x4 u, float w) {
    A.x = fmaf(w, bf2f(u.x & 0xffff), A.x); A.y = fmaf(w, bf2f(u.x >> 16), A.y);
    A.z = fmaf(w, bf2f(u.y & 0xffff), A.z); A.w = fmaf(w, bf2f(u.y >> 16), A.w);
    B.x = fmaf(w, bf2f(u.z & 0xffff), B.x); B.y = fmaf(w, bf2f(u.z >> 16), B.y);
    B.z = fmaf(w, bf2f(u.w & 0xffff), B.z); B.w = fmaf(w, bf2f(u.w >> 16), B.w);
}

__global__ __launch_bounds__(256) void span_l1_kernel(const float* __restrict__ attns,
                                                      const int* __restrict__ starts,
                                                      const int* __restrict__ lens,
                                                      const unsigned short* __restrict__ Ps,
                                                      const unsigned short* __restrict__ Pe,
                                                      const unsigned short* __restrict__ Pm,
                                                      const float* __restrict__ PW,
                                                      unsigned short* __restrict__ SH1) {
    const int wid = threadIdx.x >> 6;
    const int lane = threadIdx.x & 63;
    const int grp = lane >> 4;
    const int hl = lane & 15;
    const int gbase = lane & 48;
    const int s = blockIdx.x * 16 + wid * 4 + grp;
    const int start = starts[s];
    const int len = lens[s];

    const int iv = min(start + hl, T_TOK - 1);
    float a = (hl <= len) ? attns[iv] : -INFINITY;
    float m = a;
    #pragma unroll
    for (int off = 8; off; off >>= 1) m = fmaxf(m, __shfl_xor(m, off));
    float e = (hl <= len) ? __expf(a - m) : 0.f;
    float ssum = e;
    #pragma unroll
    for (int off = 8; off; off >>= 1) ssum += __shfl_xor(ssum, off);
    float wv = e / ssum;

    float wl[10]; int il[10];
    #pragma unroll
    for (int l = 0; l < 10; ++l) {
        wl[l] = __shfl(wv, gbase + l);
        il[l] = __shfl(iv, gbase + l) * 160;
    }

    const int end = start + len;
    const int width = len + 1;
    const int bucket = (width >= 1) + (width >= 2) + (width >= 3) + (width >= 4) +
                       (width >= 8) + (width >= 16) + (width >= 32) + (width >= 64);

    const unsigned short* ps = Ps + (size_t)start * 160;
    const unsigned short* pe = Pe + (size_t)end * 160;
    const float* pw = PW + bucket * 160;

    #pragma unroll
    for (int rep = 0; rep < 2; ++rep) {
        const int c = rep * 16 + hl;          // 16B chunk index, 20 per span
        if (c < 20) {
            const int j0 = c * 8;
            f32x4 a0 = *(const f32x4*)(pw + j0);
            f32x4 a1 = *(const f32x4*)(pw + j0 + 4);
            add_bf8(a0, a1, *(const u32x4*)(ps + j0));
            add_bf8(a0, a1, *(const u32x4*)(pe + j0));
            #pragma unroll
            for (int l = 0; l < 10; ++l)
                fma_bf8(a0, a1, *(const u32x4*)(Pm + il[l] + j0), wl[l]);
            u32x4 pk;
            pk.x = (unsigned)f2bf(fmaxf(a0.x, 0.f)) | ((unsigned)f2bf(fmaxf(a0.y, 0.f)) << 16);
            pk.y = (unsigned)f2bf(fmaxf(a0.z, 0.f)) | ((unsigned)f2bf(fmaxf(a0.w, 0.f)) << 16);
            pk.z = (unsigned)f2bf(fmaxf(a1.x, 0.f)) | ((unsigned)f2bf(fmaxf(a1.y, 0.f)) << 16);
            pk.w = (unsigned)f2bf(fmaxf(a1.z, 0.f)) | ((unsigned)f2bf(fmaxf(a1.w, 0.f)) << 16);
            *(u32x4*)(SH1 + (size_t)s * 192 + j0) = pk;
        }
    }
}

extern "C" void kernel_launch(void* const* d_in, const int* in_sizes, int n_in,
                              void* d_out, int out_size, void* d_ws, size_t ws_size,
                              hipStream_t stream) {
    const float* states = (const float*)d_in[0];
    const float* embeds = (const float*)d_in[1];
    const int* span_starts = (const int*)d_in[2];
    const int* span_lengths = (const int*)d_in[3];
    const float* Wa1 = (const float*)d_in[4];
    const float* ba1 = (const float*)d_in[5];
    const float* Wa2 = (const float*)d_in[6];
    const float* ba2 = (const float*)d_in[7];
    const float* Wa3 = (const float*)d_in[8];
    const float* ba3 = (const float*)d_in[9];
    const float* width_table = (const float*)d_in[10];
    const float* Ws1 = (const float*)d_in[11];
    const float* bs1 = (const float*)d_in[12];
    const float* Ws2 = (const float*)d_in[13];
    const float* bs2 = (const float*)d_in[14];
    const float* Ws3 = (const float*)d_in[15];
    const float* bs3 = (const float*)d_in[16];
    float* out = (float*)d_out;

    // ---- workspace layout ----
    char* w = (char*)d_ws;
    unsigned short* WtA  = (unsigned short*)w;  w += 480 * 1024 * 2;
    unsigned short* WtE  = (unsigned short*)w;  w += 160 * 512 * 2;
    unsigned short* Wa2t = (unsigned short*)w;  w += 160 * 192 * 2;
    unsigned short* Ws2t = (unsigned short*)w;  w += 160 * 192 * 2;
    float* PW    = (float*)w;                   w += 9 * 160 * 4;       // stride 160, +bs1
    float* attns = (float*)w;                   w += 8192 * 4;
    unsigned short* Psh = (unsigned short*)w;   w += (size_t)T_TOK * 160 * 2;   // bf16
    unsigned short* Peh = (unsigned short*)w;   w += (size_t)T_TOK * 160 * 2;   // bf16
    unsigned short* Pmh = (unsigned short*)w;   w += (size_t)T_TOK * 160 * 2;   // bf16
    unsigned short* SH1 = (unsigned short*)w;   w += (size_t)S_SPAN * 192 * 2;  // bf16
    // No memsets: pad cols (0xAA poison = finite bf16) multiply zeroed W rows.

    // ---- prep: LDS-tiled weight transposes + width proj (+bs1) ----
    PrepTab pt;
    pt.g[0] = { Wa1,              WtA,              1024, 1024, 3 * (1024/64) };
    pt.g[1] = { Ws1,              WtA + 160*1024,   1024, 1024, 3 * (1024/64) };
    pt.g[2] = { Ws1 + 1024*150,   WtA + 320*1024,   1024, 1024, 3 * (1024/64) };
    pt.g[3] = { Ws1 + 2048*150,   WtE,               512,  512, 3 * (512/64)  };
    pt.g[4] = { Wa2,              Wa2t,              150,  192, 3 * (192/64)  };
    pt.g[5] = { Ws2,              Ws2t,              150,  192, 3 * (192/64)  };
    pt.wt = width_table; pt.Ws1w = Ws1 + 2560*150; pt.bs1 = bs1; pt.PW = PW;
    int wblk = 0; for (int i = 0; i < 6; ++i) wblk += pt.g[i].nblk;
    prep_kernel<<<wblk + 9, 256, 0, stream>>>(pt);

    GG z = {};

    // ---- fused GEMM1+2 + attn layers 2/3: 4 groups, 512 blocks ----
    GTab t1; t1.ng = 4;
    t1.g[0] = z; t1.g[0].A = states; t1.g[0].lda = 1024; t1.g[0].W = WtA;            t1.g[0].K = 1024;
    t1.g[0].nrb = 128; t1.g[0].bias = ba1;
    t1.g[0].W2 = Wa2t; t1.g[0].bias2 = ba2;
    t1.g[0].dotv = Wa3; t1.g[0].dotb = ba3; t1.g[0].dotout = attns;
    t1.g[1] = z; t1.g[1].A = states; t1.g[1].lda = 1024; t1.g[1].W = WtA + 160*1024; t1.g[1].K = 1024;
    t1.g[1].nrb = 128; t1.g[1].outh = Psh; t1.g[1].ldo = 160;
    t1.g[2] = z; t1.g[2].A = states; t1.g[2].lda = 1024; t1.g[2].W = WtA + 320*1024; t1.g[2].K = 1024;
    t1.g[2].nrb = 128; t1.g[2].outh = Peh; t1.g[2].ldo = 160;
    t1.g[3] = z; t1.g[3].A = embeds; t1.g[3].lda = 512;  t1.g[3].W = WtE;            t1.g[3].K = 512;
    t1.g[3].nrb = 128; t1.g[3].outh = Pmh; t1.g[3].ldo = 160;
    gemm_fused<1, true><<<512, 256, 0, stream>>>(t1);

    // ---- span layer1 -> SH1 (bf16), 16 spans/block, 2048 blocks ----
    span_l1_kernel<<<S_SPAN / 16, 256, 0, stream>>>(attns, span_starts, span_lengths,
                                                    Psh, Peh, Pmh, PW, SH1);

    // ---- span layer2 + fused layer3 dot -> out (K=192) ----
    GTab t3; t3.ng = 1;
    t3.g[0] = z; t3.g[0].A = SH1; t3.g[0].lda = 192; t3.g[0].W = Ws2t; t3.g[0].K = 192;
    t3.g[0].nrb = 512; t3.g[0].bias = bs2; t3.g[0].dotv = Ws3; t3.g[0].dotb = bs3; t3.g[0].dotout = out;
    gemm_fused<3, false><<<512, 256, 0, stream>>>(t3);
}

// Round 8
// 166.930 us; speedup vs baseline: 1.5410x; 1.5410x over previous
//
#include <hip/hip_runtime.h>
#include <math.h>

#define T_TOK 8192
#define A_DIM 1024
#define E_DIM 512
#define S_SPAN 32768
#define HID 150

typedef __attribute__((ext_vector_type(8))) short short8;
typedef __attribute__((ext_vector_type(4))) float f32x4;
typedef __attribute__((ext_vector_type(4))) unsigned int u32x4;

__device__ __forceinline__ unsigned short f2bf(float f) {
    unsigned int u = __builtin_bit_cast(unsigned int, f);
    u += 0x7FFFu + ((u >> 16) & 1u);          // RNE
    return (unsigned short)(u >> 16);
}
__device__ __forceinline__ float bf2f(unsigned int h16) {
    unsigned int u = h16 << 16;
    return __builtin_bit_cast(float, u);
}
__device__ __forceinline__ short8 cast8(f32x4 a, f32x4 b) {
    short8 r;
    r[0] = (short)f2bf(a.x); r[1] = (short)f2bf(a.y);
    r[2] = (short)f2bf(a.z); r[3] = (short)f2bf(a.w);
    r[4] = (short)f2bf(b.x); r[5] = (short)f2bf(b.y);
    r[6] = (short)f2bf(b.z); r[7] = (short)f2bf(b.w);
    return r;
}

// Publish-barrier: ds ops retired (lgkmcnt 0) but VMEM loads stay IN FLIGHT
// across the barrier (no vmcnt drain — unlike __syncthreads).
__device__ __forceinline__ void pub_barrier() {
    __builtin_amdgcn_sched_barrier(0);
    asm volatile("s_waitcnt lgkmcnt(0)" ::: "memory");
    __builtin_amdgcn_sched_barrier(0);
    __builtin_amdgcn_s_barrier();
    __builtin_amdgcn_sched_barrier(0);
}

// ---------------------------------------------------------------------------
// prep: weight transposes (LDS 64x64 tiles) + width projection (+bs1) +
// NEW (r8): bf16 pre-cast of states/embeds. The f32->bf16 cast8 in gemm1
// cost ~250 VALU cyc per chunk per wave (more than the MFMAs it fed) and
// ran 3x redundantly for states. One streaming pass here (~10 us HBM-bound)
// removes it from gemm1's critical path entirely. Bit-identical values.
// ---------------------------------------------------------------------------
struct WConv { const float* src; unsigned short* dst; int K0; int Kpad; int nblk; };
struct PrepTab {
    WConv g[6];
    const float* wt; const float* Ws1w; const float* bs1; float* PW;
    const float* castS; unsigned short* castSd;   // states: 4096 blocks
    const float* castE; unsigned short* castEd;   // embeds: 2048 blocks
};

__global__ __launch_bounds__(256) void prep_kernel(PrepTab tab) {
    __shared__ float tl[64][65];                 // stride 65: conflict-free transpose
    int b = blockIdx.x;
    #pragma unroll
    for (int gi = 0; gi < 6; ++gi) {
        if (b < tab.g[gi].nblk) {
            const int kt   = tab.g[gi].Kpad >> 6;        // k-tiles
            const int j0   = (b / kt) * 64;              // output-row tile base
            const int k0   = (b % kt) * 64;              // k tile base
            const int K0   = tab.g[gi].K0;
            const int Kpad = tab.g[gi].Kpad;
            const int ty = threadIdx.x >> 6, tx = threadIdx.x & 63;
            const float* src = tab.g[gi].src;
            #pragma unroll
            for (int r = 0; r < 16; ++r) {               // coalesced src reads
                int k = k0 + ty * 16 + r;
                int j = j0 + tx;
                tl[ty * 16 + r][tx] = (j < HID && k < K0)
                                      ? src[(size_t)k * HID + j] : 0.f;
            }
            __syncthreads();
            unsigned short* dst = tab.g[gi].dst;
            #pragma unroll
            for (int r = 0; r < 16; ++r) {               // coalesced dst writes
                int j = j0 + ty * 16 + r;
                if (j < 160)
                    dst[(size_t)j * Kpad + k0 + tx] = f2bf(tl[tx][ty * 16 + r]);
            }
            return;
        }
        b -= tab.g[gi].nblk;
    }
    if (b < 9) {
        // width projection: PW row = width_table[b] @ Ws1w + bs1,
        // stride 160 with exact zeros at j>=150.
        int j = threadIdx.x;
        if (j < 160) {
            float acc = 0.f;
            if (j < HID) {
                for (int k = 0; k < 20; ++k)
                    acc = fmaf(tab.wt[b * 20 + k], tab.Ws1w[k * HID + j], acc);
                acc += tab.bs1[j];
            }
            tab.PW[b * 160 + j] = acc;
        }
        return;
    }
    b -= 9;
    // bf16 pre-cast: 2048 elems/block (8/thread), coalesced both sides.
    const float* src; unsigned short* dst;
    size_t base;
    if (b < 4096) { src = tab.castS; dst = tab.castSd; base = (size_t)b * 2048; }
    else          { src = tab.castE; dst = tab.castEd; base = (size_t)(b - 4096) * 2048; }
    const size_t i = base + (size_t)threadIdx.x * 8;
    f32x4 f0 = *(const f32x4*)(src + i);
    f32x4 f1 = *(const f32x4*)(src + i + 4);
    *(short8*)(dst + i) = cast8(f0, f1);
}

// ---------------------------------------------------------------------------
// unified MFMA GEMM (r6 structure restored after r7's direct-stream failure:
// LDS staging amortizes B across 4 waves and converts 20 dependent ~200cyc
// L2 gathers/chunk into 5 staged loads + ds_reads — r7 proved its value by
// deletion: 44 -> 117 us). 2-deep pipelined K-loop, STATIC register sets,
// counted-wait pub_barrier, odd-nch tail (gemm3 K=192 -> nch=3).
// r8: A is ALWAYS bf16 now (pre-cast in prep) — fA/cast8 path deleted.
// Bit-identical accumulation order.
// ---------------------------------------------------------------------------
struct GG {
    const void* A; int lda;
    const unsigned short* W; int K; int nrb;
    unsigned short* outh; int ldo;
    const float* bias; int relu;
    const float* dotv; const float* dotb; float* dotout;
    const unsigned short* W2; const float* bias2;
};
struct GTab { GG g[4]; int ng; };

template <int TAG>
__global__ __launch_bounds__(256) void gemm_fused(GTab tab) {
    constexpr int LDW = 72;
    __shared__ unsigned short WtL[2][160 * LDW];

    int b = blockIdx.x;
    int gi = 0;
    while (gi < tab.ng - 1 && b >= tab.g[gi].nrb) { b -= tab.g[gi].nrb; ++gi; }
    const GG G = tab.g[gi];

    const int tid = threadIdx.x;
    const int wid = tid >> 6;
    const int lane = tid & 63;
    const int l15 = lane & 15;
    const int quad = lane >> 4;
    const int row0 = b * 64 + wid * 16 + l15;
    const int K = G.K;
    const int nch = K >> 6;                       // 16 (K=1024), 8 (512), 3 (192)
    const unsigned short* Ah = (const unsigned short*)G.A + (size_t)row0 * G.lda;

    int sn[5], sk[5];
    #pragma unroll
    for (int i = 0; i < 5; ++i) { int u = tid + i * 256; sn[i] = u >> 3; sk[i] = (u & 7) * 8; }

    f32x4 acc[10];
    #pragma unroll
    for (int nt = 0; nt < 10; ++nt) acc[nt] = (f32x4){0.f, 0.f, 0.f, 0.f};

    // named 2-deep register sets — ALL statically indexed (rule #20)
    u32x4 wA[5], wB[5];
    short8 hAa[2], hAb[2];
    short8 avc0, avc1;

#define LOAD_W(SET, KOFF)                                                     \
    {   _Pragma("unroll")                                                     \
        for (int i = 0; i < 5; ++i)                                           \
            SET[i] = *(const u32x4*)(G.W + (size_t)sn[i] * K + (KOFF) + sk[i]); }
#define LOAD_A(HSET, KOFF)                                                    \
    {   HSET[0] = *(const short8*)(Ah + (KOFF) + quad * 8);                   \
        HSET[1] = *(const short8*)(Ah + (KOFF) + 32 + quad * 8); }
#define STORE_W(SET, BUF)                                                     \
    {   _Pragma("unroll")                                                     \
        for (int i = 0; i < 5; ++i)                                           \
            *(u32x4*)&WtL[BUF][sn[i] * LDW + sk[i]] = SET[i]; }
#define SET_AVC(HSET)                                                         \
    {   avc0 = HSET[0]; avc1 = HSET[1]; }
#define MFMA_BLOCK(BUF)                                                       \
    {   _Pragma("unroll")                                                     \
        for (int nt = 0; nt < 10; ++nt) {                                     \
            short8 bv0 = *(const short8*)&WtL[BUF][(nt * 16 + l15) * LDW + quad * 8]; \
            acc[nt] = __builtin_amdgcn_mfma_f32_16x16x32_bf16(avc0, bv0, acc[nt], 0, 0, 0); \
            short8 bv1 = *(const short8*)&WtL[BUF][(nt * 16 + l15) * LDW + 32 + quad * 8]; \
            acc[nt] = __builtin_amdgcn_mfma_f32_16x16x32_bf16(avc1, bv1, acc[nt], 0, 0, 0); \
        } }

    // ---- prologue: issue chunk 0 AND chunk 1 loads before any wait ----
    LOAD_W(wA, 0);
    LOAD_A(hAa, 0);
    LOAD_W(wB, 64);
    LOAD_A(hAb, 64);
    STORE_W(wA, 0);
    SET_AVC(hAa);
    pub_barrier();

    for (int c = 0; c + 1 < nch; c += 2) {
        // ---- even chunk c (LDS buf 0) ----
        const bool mA = (c + 2 < nch);
        if (mA) {
            const int kn = (c + 2) << 6;
            LOAD_W(wA, kn);
            LOAD_A(hAa, kn);
        }
        STORE_W(wB, 1);                     // chunk c+1: loaded a full chunk ago
        MFMA_BLOCK(0);                      // chunk c
        SET_AVC(hAb);                       // A operand for chunk c+1
        pub_barrier();

        // ---- odd chunk c+1 (LDS buf 1) ----
        const bool mB = (c + 3 < nch);
        if (mB) {
            const int kn = (c + 3) << 6;
            LOAD_W(wB, kn);
            LOAD_A(hAb, kn);
        }
        if (mA) STORE_W(wA, 0);             // chunk c+2
        MFMA_BLOCK(1);                      // chunk c+1
        if (mA) SET_AVC(hAa);               // A operand for chunk c+2
        pub_barrier();
    }
    if (nch & 1) {
        // tail chunk nch-1: stored into buf0 at the last pair's odd phase,
        // avc already = A[nch-1]; trailing pub_barrier ordered the stores.
        MFMA_BLOCK(0);
    }

#undef LOAD_W
#undef LOAD_A
#undef STORE_W
#undef SET_AVC
#undef MFMA_BLOCK

    const int rbase = b * 64 + wid * 16 + quad * 4;
    if (G.W2) {
        // ---- fused attn layer2+3 ----
        constexpr int LDH = 168;
        unsigned short* tile = &WtL[0][0] + wid * 16 * LDH;   // per-wave region
        #pragma unroll
        for (int nt = 0; nt < 10; ++nt) {
            int col = nt * 16 + l15;
            float bv_ = (col < HID) ? G.bias[col] : 0.f;
            #pragma unroll
            for (int r = 0; r < 4; ++r) {
                float v = fmaxf(acc[nt][r] + bv_, 0.f);
                tile[(quad * 4 + r) * LDH + col] = f2bf(v);
            }
        }
        // same-wave RAW through LDS: compiler inserts lgkmcnt; no barrier.
        f32x4 acc2[10];
        #pragma unroll
        for (int nt = 0; nt < 10; ++nt) acc2[nt] = (f32x4){0.f, 0.f, 0.f, 0.f};
        #pragma unroll
        for (int kc = 0; kc < 5; ++kc) {
            short8 av = *(const short8*)&tile[l15 * LDH + kc * 32 + quad * 8];
            #pragma unroll
            for (int nt = 0; nt < 10; ++nt) {
                short8 bv = *(const short8*)(G.W2 + (size_t)(nt * 16 + l15) * 192 + kc * 32 + quad * 8);
                acc2[nt] = __builtin_amdgcn_mfma_f32_16x16x32_bf16(av, bv, acc2[nt], 0, 0, 0);
            }
        }
        float part[4] = {0.f, 0.f, 0.f, 0.f};
        #pragma unroll
        for (int nt = 0; nt < 10; ++nt) {
            int col = nt * 16 + l15;
            float b2 = (col < HID) ? G.bias2[col] : 0.f;
            float vv = (col < HID) ? G.dotv[col] : 0.f;
            #pragma unroll
            for (int r = 0; r < 4; ++r)
                part[r] += fmaxf(acc2[nt][r] + b2, 0.f) * vv;
        }
        #pragma unroll
        for (int r = 0; r < 4; ++r) {
            float p = part[r];
            #pragma unroll
            for (int off = 1; off < 16; off <<= 1) p += __shfl_xor(p, off);
            if (l15 == 0) G.dotout[rbase + r] = p + G.dotb[0];
        }
    } else if (G.dotout) {
        float part[4] = {0.f, 0.f, 0.f, 0.f};
        #pragma unroll
        for (int nt = 0; nt < 10; ++nt) {
            int col = nt * 16 + l15;
            float bv_ = (col < HID) ? G.bias[col] : 0.f;
            float vv = (col < HID) ? G.dotv[col] : 0.f;
            #pragma unroll
            for (int r = 0; r < 4; ++r)
                part[r] += fmaxf(acc[nt][r] + bv_, 0.f) * vv;
        }
        #pragma unroll
        for (int r = 0; r < 4; ++r) {
            float p = part[r];
            #pragma unroll
            for (int off = 1; off < 16; off <<= 1) p += __shfl_xor(p, off);
            if (l15 == 0) G.dotout[rbase + r] = p + G.dotb[0];
        }
    } else {
        #pragma unroll
        for (int nt = 0; nt < 10; ++nt) {
            int col = nt * 16 + l15;
            float bv_ = (G.bias != nullptr && col < HID) ? G.bias[col] : 0.f;
            #pragma unroll
            for (int r = 0; r < 4; ++r) {
                int row = rbase + r;
                float v = acc[nt][r] + bv_;
                if (G.relu) v = fmaxf(v, 0.f);
                G.outh[(size_t)row * G.ldo + col] = f2bf(v);
            }
        }
    }
}

// ---------------------------------------------------------------------------
// span layer-1 (2048 blocks, 32 waves/CU): one span per 16-lane group.
// dwordx4 gathers (r7): thread hl handles 16B chunk hl (and 16+hl if hl<4).
// Same per-element FMA chain -> bit-identical. Chunks 16..19 cover cols
// 128..159; cols 150..159 compute exact zeros over gemm3's zero B rows.
// ---------------------------------------------------------------------------
__device__ __forceinline__ void add_bf8(f32x4& A, f32x4& B, u32x4 u) {
    A.x += bf2f(u.x & 0xffff); A.y += bf2f(u.x >> 16);
    A.z += bf2f(u.y & 0xffff); A.w += bf2f(u.y >> 16);
    B.x += bf2f(u.z & 0xffff); B.y += bf2f(u.z >> 16);
    B.z += bf2f(u.w & 0xffff); B.w += bf2f(u.w >> 16);
}
__device__ __forceinline__ void fma_bf8(f32x4& A, f32x4& B, u32x4 u, float w) {
    A.x = fmaf(w, bf2f(u.x & 0xffff), A.x); A.y = fmaf(w, bf2f(u.x >> 16), A.y);
    A.z = fmaf(w, bf2f(u.y & 0xffff), A.z); A.w = fmaf(w, bf2f(u.y >> 16), A.w);
    B.x = fmaf(w, bf2f(u.z & 0xffff), B.x); B.y = fmaf(w, bf2f(u.z >> 16), B.y);
    B.z = fmaf(w, bf2f(u.w & 0xffff), B.z); B.w = fmaf(w, bf2f(u.w >> 16), B.w);
}

__global__ __launch_bounds__(256) void span_l1_kernel(const float* __restrict__ attns,
                                                      const int* __restrict__ starts,
                                                      const int* __restrict__ lens,
                                                      const unsigned short* __restrict__ Ps,
                                                      const unsigned short* __restrict__ Pe,
                                                      const unsigned short* __restrict__ Pm,
                                                      const float* __restrict__ PW,
                                                      unsigned short* __restrict__ SH1) {
    const int wid = threadIdx.x >> 6;
    const int lane = threadIdx.x & 63;
    const int grp = lane >> 4;
    const int hl = lane & 15;
    const int gbase = lane & 48;
    const int s = blockIdx.x * 16 + wid * 4 + grp;
    const int start = starts[s];
    const int len = lens[s];

    const int iv = min(start + hl, T_TOK - 1);
    float a = (hl <= len) ? attns[iv] : -INFINITY;
    float m = a;
    #pragma unroll
    for (int off = 8; off; off >>= 1) m = fmaxf(m, __shfl_xor(m, off));
    float e = (hl <= len) ? __expf(a - m) : 0.f;
    float ssum = e;
    #pragma unroll
    for (int off = 8; off; off >>= 1) ssum += __shfl_xor(ssum, off);
    float wv = e / ssum;

    float wl[10]; int il[10];
    #pragma unroll
    for (int l = 0; l < 10; ++l) {
        wl[l] = __shfl(wv, gbase + l);
        il[l] = __shfl(iv, gbase + l) * 160;
    }

    const int end = start + len;
    const int width = len + 1;
    const int bucket = (width >= 1) + (width >= 2) + (width >= 3) + (width >= 4) +
                       (width >= 8) + (width >= 16) + (width >= 32) + (width >= 64);

    const unsigned short* ps = Ps + (size_t)start * 160;
    const unsigned short* pe = Pe + (size_t)end * 160;
    const float* pw = PW + bucket * 160;

    #pragma unroll
    for (int rep = 0; rep < 2; ++rep) {
        const int c = rep * 16 + hl;          // 16B chunk index, 20 per span
        if (c < 20) {
            const int j0 = c * 8;
            f32x4 a0 = *(const f32x4*)(pw + j0);
            f32x4 a1 = *(const f32x4*)(pw + j0 + 4);
            add_bf8(a0, a1, *(const u32x4*)(ps + j0));
            add_bf8(a0, a1, *(const u32x4*)(pe + j0));
            #pragma unroll
            for (int l = 0; l < 10; ++l)
                fma_bf8(a0, a1, *(const u32x4*)(Pm + il[l] + j0), wl[l]);
            u32x4 pk;
            pk.x = (unsigned)f2bf(fmaxf(a0.x, 0.f)) | ((unsigned)f2bf(fmaxf(a0.y, 0.f)) << 16);
            pk.y = (unsigned)f2bf(fmaxf(a0.z, 0.f)) | ((unsigned)f2bf(fmaxf(a0.w, 0.f)) << 16);
            pk.z = (unsigned)f2bf(fmaxf(a1.x, 0.f)) | ((unsigned)f2bf(fmaxf(a1.y, 0.f)) << 16);
            pk.w = (unsigned)f2bf(fmaxf(a1.z, 0.f)) | ((unsigned)f2bf(fmaxf(a1.w, 0.f)) << 16);
            *(u32x4*)(SH1 + (size_t)s * 192 + j0) = pk;
        }
    }
}

extern "C" void kernel_launch(void* const* d_in, const int* in_sizes, int n_in,
                              void* d_out, int out_size, void* d_ws, size_t ws_size,
                              hipStream_t stream) {
    const float* states = (const float*)d_in[0];
    const float* embeds = (const float*)d_in[1];
    const int* span_starts = (const int*)d_in[2];
    const int* span_lengths = (const int*)d_in[3];
    const float* Wa1 = (const float*)d_in[4];
    const float* ba1 = (const float*)d_in[5];
    const float* Wa2 = (const float*)d_in[6];
    const float* ba2 = (const float*)d_in[7];
    const float* Wa3 = (const float*)d_in[8];
    const float* ba3 = (const float*)d_in[9];
    const float* width_table = (const float*)d_in[10];
    const float* Ws1 = (const float*)d_in[11];
    const float* bs1 = (const float*)d_in[12];
    const float* Ws2 = (const float*)d_in[13];
    const float* bs2 = (const float*)d_in[14];
    const float* Ws3 = (const float*)d_in[15];
    const float* bs3 = (const float*)d_in[16];
    float* out = (float*)d_out;

    // ---- workspace layout ----
    char* w = (char*)d_ws;
    unsigned short* WtA  = (unsigned short*)w;  w += 480 * 1024 * 2;
    unsigned short* WtE  = (unsigned short*)w;  w += 160 * 512 * 2;
    unsigned short* Wa2t = (unsigned short*)w;  w += 160 * 192 * 2;
    unsigned short* Ws2t = (unsigned short*)w;  w += 160 * 192 * 2;
    float* PW    = (float*)w;                   w += 9 * 160 * 4;       // stride 160, +bs1
    float* attns = (float*)w;                   w += 8192 * 4;
    unsigned short* Psh = (unsigned short*)w;   w += (size_t)T_TOK * 160 * 2;   // bf16
    unsigned short* Peh = (unsigned short*)w;   w += (size_t)T_TOK * 160 * 2;   // bf16
    unsigned short* Pmh = (unsigned short*)w;   w += (size_t)T_TOK * 160 * 2;   // bf16
    unsigned short* SH1 = (unsigned short*)w;   w += (size_t)S_SPAN * 192 * 2;  // bf16
    unsigned short* SB  = (unsigned short*)w;   w += (size_t)T_TOK * A_DIM * 2; // states bf16
    unsigned short* EB  = (unsigned short*)w;   w += (size_t)T_TOK * E_DIM * 2; // embeds bf16
    // No memsets: pad cols (0xAA poison = finite bf16) multiply zeroed W rows.

    // ---- prep: transposes + width proj + bf16 pre-cast (90+9+6144 blocks) ----
    PrepTab pt;
    pt.g[0] = { Wa1,              WtA,              1024, 1024, 3 * (1024/64) };
    pt.g[1] = { Ws1,              WtA + 160*1024,   1024, 1024, 3 * (1024/64) };
    pt.g[2] = { Ws1 + 1024*150,   WtA + 320*1024,   1024, 1024, 3 * (1024/64) };
    pt.g[3] = { Ws1 + 2048*150,   WtE,               512,  512, 3 * (512/64)  };
    pt.g[4] = { Wa2,              Wa2t,              150,  192, 3 * (192/64)  };
    pt.g[5] = { Ws2,              Ws2t,              150,  192, 3 * (192/64)  };
    pt.wt = width_table; pt.Ws1w = Ws1 + 2560*150; pt.bs1 = bs1; pt.PW = PW;
    pt.castS = states; pt.castSd = SB;
    pt.castE = embeds; pt.castEd = EB;
    int wblk = 0; for (int i = 0; i < 6; ++i) wblk += pt.g[i].nblk;
    prep_kernel<<<wblk + 9 + 4096 + 2048, 256, 0, stream>>>(pt);

    GG z = {};

    // ---- fused GEMM1+2 + attn layers 2/3: 4 groups, 512 blocks ----
    GTab t1; t1.ng = 4;
    t1.g[0] = z; t1.g[0].A = SB; t1.g[0].lda = 1024; t1.g[0].W = WtA;            t1.g[0].K = 1024;
    t1.g[0].nrb = 128; t1.g[0].bias = ba1;
    t1.g[0].W2 = Wa2t; t1.g[0].bias2 = ba2;
    t1.g[0].dotv = Wa3; t1.g[0].dotb = ba3; t1.g[0].dotout = attns;
    t1.g[1] = z; t1.g[1].A = SB; t1.g[1].lda = 1024; t1.g[1].W = WtA + 160*1024; t1.g[1].K = 1024;
    t1.g[1].nrb = 128; t1.g[1].outh = Psh; t1.g[1].ldo = 160;
    t1.g[2] = z; t1.g[2].A = SB; t1.g[2].lda = 1024; t1.g[2].W = WtA + 320*1024; t1.g[2].K = 1024;
    t1.g[2].nrb = 128; t1.g[2].outh = Peh; t1.g[2].ldo = 160;
    t1.g[3] = z; t1.g[3].A = EB; t1.g[3].lda = 512;  t1.g[3].W = WtE;            t1.g[3].K = 512;
    t1.g[3].nrb = 128; t1.g[3].outh = Pmh; t1.g[3].ldo = 160;
    gemm_fused<1><<<512, 256, 0, stream>>>(t1);

    // ---- span layer1 -> SH1 (bf16), 16 spans/block, 2048 blocks ----
    span_l1_kernel<<<S_SPAN / 16, 256, 0, stream>>>(attns, span_starts, span_lengths,
                                                    Psh, Peh, Pmh, PW, SH1);

    // ---- span layer2 + fused layer3 dot -> out (K=192, odd-nch tail) ----
    GTab t3; t3.ng = 1;
    t3.g[0] = z; t3.g[0].A = SH1; t3.g[0].lda = 192; t3.g[0].W = Ws2t; t3.g[0].K = 192;
    t3.g[0].nrb = 512; t3.g[0].bias = bs2; t3.g[0].dotv = Ws3; t3.g[0].dotb = bs3; t3.g[0].dotout = out;
    gemm_fused<3><<<512, 256, 0, stream>>>(t3);
}